// Round 5
// baseline (8060.262 us; speedup 1.0000x reference)
//
#include <hip/hip_runtime.h>
#include <math.h>

#define NTOK 768
#define CS   384
#define CZ   128
#define NH   12
#define INF_ 100000.0f
#define EPS_ 1e-8f

typedef unsigned int  uint32;
typedef unsigned short ushort16;

__device__ __forceinline__ uint32 bf16rn(float x) {
    uint32 u = __float_as_uint(x);
    return (u + 0x7fffu + ((u >> 16) & 1u)) >> 16;
}
__device__ __forceinline__ float bflo(uint32 u) { return __uint_as_float((u & 0xffffu) << 16); }
__device__ __forceinline__ float bfhi(uint32 u) { return __uint_as_float(u & 0xffff0000u); }

// ---------------------------------------------------------------------------
// K1: s-projections + rigid transform. 4 tokens/block to amortize weight reads.
// Outputs: Q[n][h*16+c], KT[h*16+c][n], VT[h*16+c][n],
//          QP[n][(h*4+p)*3+x], KPT[(h*4+p)*3+x][n], VPT[(h*8+p)*3+x][n]
// ---------------------------------------------------------------------------
#define K1T 4
__global__ __launch_bounds__(256) void k1_proj(
    const float* __restrict__ s, const float* __restrict__ rot, const float* __restrict__ trans,
    const float* __restrict__ wq, const float* __restrict__ bq,
    const float* __restrict__ wkv, const float* __restrict__ bkv,
    const float* __restrict__ wqp, const float* __restrict__ bqp,
    const float* __restrict__ wkvp, const float* __restrict__ bkvp,
    float* __restrict__ Q, float* __restrict__ KT, float* __restrict__ VT,
    float* __restrict__ QP, float* __restrict__ KPT, float* __restrict__ VPT)
{
    __shared__ float sL[K1T][CS];
    __shared__ float rotL[K1T][9], transL[K1T][3];
    const int n0 = blockIdx.x * K1T, tid = threadIdx.x;

    for (int idx = tid; idx < K1T * CS; idx += 256) {
        const int t = idx / CS, k = idx % CS;
        sL[t][k] = s[(n0 + t) * CS + k];
    }
    if (tid < K1T * 9)  rotL[tid / 9][tid % 9] = rot[n0 * 9 + tid];
    if (tid >= 64 && tid < 64 + K1T * 3) {
        const int q = tid - 64;
        transL[q / 3][q % 3] = trans[n0 * 3 + q];
    }
    __syncthreads();

    for (int item = tid; item < 768; item += 256) {
        if (item < 192) {                       // q
            const int col = item;
            float acc[K1T];
            #pragma unroll
            for (int t = 0; t < K1T; t++) acc[t] = bq[col];
            for (int k = 0; k < CS; k++) {
                const float w = wq[k * 192 + col];
                #pragma unroll
                for (int t = 0; t < K1T; t++) acc[t] += sL[t][k] * w;
            }
            #pragma unroll
            for (int t = 0; t < K1T; t++) Q[(n0 + t) * 192 + col] = acc[t];
        } else if (item < 576) {                // k, v (kv cols: h*32 + [0..15]=k, [16..31]=v)
            const int r = item - 192;
            const bool isV = (r >= 192);
            const int idx = isV ? r - 192 : r;  // h*16+c
            const int h = idx >> 4, c = idx & 15;
            const int col = h * 32 + (isV ? 16 : 0) + c;
            float acc[K1T];
            #pragma unroll
            for (int t = 0; t < K1T; t++) acc[t] = bkv[col];
            for (int k = 0; k < CS; k++) {
                const float w = wkv[k * 384 + col];
                #pragma unroll
                for (int t = 0; t < K1T; t++) acc[t] += sL[t][k] * w;
            }
            #pragma unroll
            for (int t = 0; t < K1T; t++) {
                if (isV) VT[idx * NTOK + (n0 + t)] = acc[t];
                else     KT[idx * NTOK + (n0 + t)] = acc[t];
            }
        } else if (item < 624) {                // q points: pidx = h*4+p in [0,48)
            const int pidx = item - 576;
            float raw[K1T][3];
            #pragma unroll
            for (int x = 0; x < 3; x++) {
                const int col = x * 48 + pidx;
                float acc[K1T];
                #pragma unroll
                for (int t = 0; t < K1T; t++) acc[t] = bqp[col];
                for (int k = 0; k < CS; k++) {
                    const float w = wqp[k * 144 + col];
                    #pragma unroll
                    for (int t = 0; t < K1T; t++) acc[t] += sL[t][k] * w;
                }
                #pragma unroll
                for (int t = 0; t < K1T; t++) raw[t][x] = acc[t];
            }
            #pragma unroll
            for (int t = 0; t < K1T; t++)
                #pragma unroll
                for (int x = 0; x < 3; x++) {
                    const float v = rotL[t][x*3+0]*raw[t][0] + rotL[t][x*3+1]*raw[t][1]
                                  + rotL[t][x*3+2]*raw[t][2] + transL[t][x];
                    QP[(n0 + t) * 144 + pidx * 3 + x] = v;
                }
        } else {                                // kv points: pidx = h*12+pp in [0,144)
            const int pidx = item - 624;
            float raw[K1T][3];
            #pragma unroll
            for (int x = 0; x < 3; x++) {
                const int col = x * 144 + pidx;
                float acc[K1T];
                #pragma unroll
                for (int t = 0; t < K1T; t++) acc[t] = bkvp[col];
                for (int k = 0; k < CS; k++) {
                    const float w = wkvp[k * 432 + col];
                    #pragma unroll
                    for (int t = 0; t < K1T; t++) acc[t] += sL[t][k] * w;
                }
                #pragma unroll
                for (int t = 0; t < K1T; t++) raw[t][x] = acc[t];
            }
            const int h = pidx / 12, pp = pidx % 12;
            #pragma unroll
            for (int t = 0; t < K1T; t++)
                #pragma unroll
                for (int x = 0; x < 3; x++) {
                    const float v = rotL[t][x*3+0]*raw[t][0] + rotL[t][x*3+1]*raw[t][1]
                                  + rotL[t][x*3+2]*raw[t][2] + transL[t][x];
                    if (pp < 4) KPT[((h * 4 + pp) * 3 + x) * NTOK + (n0 + t)] = v;
                    else        VPT[((h * 8 + (pp - 4)) * 3 + x) * NTOK + (n0 + t)] = v;
                }
        }
    }
}

// ---------------------------------------------------------------------------
// K2: z projections, streaming. BBT[i][h][j] f32; PZT[i][j][c] bf16 (packed).
// grid (3, 768): by=i, j = bx*256+tid. Software-pipelined 4xfloat4 loads.
// ---------------------------------------------------------------------------
__global__ __launch_bounds__(256, 5) void k2_zproj(
    const float* __restrict__ z, const float* __restrict__ wb, const float* __restrict__ bb,
    const float* __restrict__ wdz, const float* __restrict__ bdz,
    float* __restrict__ BBT, ushort16* __restrict__ PZT)
{
    __shared__ float wL[CZ * 44];     // [k][44]: o<12 -> wb, else wdz
    __shared__ float biasL[44];
    const int tid = threadIdx.x;
    for (int idx = tid; idx < CZ * 44; idx += 256) {
        const int k = idx / 44, o = idx % 44;
        wL[idx] = (o < 12) ? wb[k * 12 + o] : wdz[k * 32 + (o - 12)];
    }
    if (tid < 44) biasL[tid] = (tid < 12) ? bb[tid] : bdz[tid - 12];
    __syncthreads();

    const int i = blockIdx.y;
    const int j = blockIdx.x * 256 + tid;
    const float4* zrow = (const float4*)(z + ((size_t)i * NTOK + j) * CZ);

    float acc[44];
    #pragma unroll
    for (int o = 0; o < 44; o++) acc[o] = biasL[o];

    float4 cur[4], nxt[4];
    #pragma unroll
    for (int t = 0; t < 4; t++) cur[t] = zrow[t];
    for (int kb = 0; kb < 8; kb++) {
        if (kb < 7) {
            #pragma unroll
            for (int t = 0; t < 4; t++) nxt[t] = zrow[(kb + 1) * 4 + t];
        }
        #pragma unroll
        for (int t = 0; t < 4; t++) {
            const float* w0 = &wL[(kb * 16 + t * 4) * 44];
            const float4 zv = cur[t];
            #pragma unroll
            for (int o = 0; o < 44; o++)
                acc[o] += zv.x * w0[o] + zv.y * w0[o + 44] + zv.z * w0[o + 88] + zv.w * w0[o + 132];
        }
        if (kb < 7) {
            #pragma unroll
            for (int t = 0; t < 4; t++) cur[t] = nxt[t];
        }
    }

    #pragma unroll
    for (int h = 0; h < 12; h++) BBT[((size_t)i * 12 + h) * NTOK + j] = acc[h];

    uint32 pk[16];
    #pragma unroll
    for (int c2 = 0; c2 < 16; c2++)
        pk[c2] = bf16rn(acc[12 + 2 * c2]) | (bf16rn(acc[12 + 2 * c2 + 1]) << 16);
    uint4* dst = (uint4*)(PZT + ((size_t)i * NTOK + j) * 32);   // 64B/thread, coalesced
    dst[0] = make_uint4(pk[0],  pk[1],  pk[2],  pk[3]);
    dst[1] = make_uint4(pk[4],  pk[5],  pk[6],  pk[7]);
    dst[2] = make_uint4(pk[8],  pk[9],  pk[10], pk[11]);
    dst[3] = make_uint4(pk[12], pk[13], pk[14], pk[15]);
}

// ---------------------------------------------------------------------------
// K3: attention per row i. LDS 38 KB -> 2 blocks/CU (24 waves).
// ---------------------------------------------------------------------------
__global__ __launch_bounds__(768, 6) void k3_attn(
    const float* __restrict__ KT, const float* __restrict__ VT,
    const float* __restrict__ KPT, const float* __restrict__ VPT,
    const float* __restrict__ Q, const float* __restrict__ QP,
    const float* __restrict__ BBT, const ushort16* __restrict__ PZT,
    const float* __restrict__ mask, const float* __restrict__ head_weights,
    float* __restrict__ O, float* __restrict__ OPT, float* __restrict__ OPAIR)
{
    __shared__ float LB[NH][NTOK];      // logits -> probs in place
    __shared__ float qrow[192], qprow[144], hwL[NH];
    const int i = blockIdx.x, tid = threadIdx.x;

    if (tid < 192) qrow[tid] = Q[i * 192 + tid];
    else if (tid >= 256 && tid < 400) qprow[tid - 256] = QP[i * 144 + (tid - 256)];
    else if (tid >= 448 && tid < 460)
        hwL[tid - 448] = logf(1.0f + expf(head_weights[tid - 448])) * 0.13608276348795434f; // sqrt(1/54)
    __syncthreads();

    const float qk_scale = 0.14433756729740643f;   // sqrt(1/48)
    const float b_scale  = 0.5773502691896258f;    // sqrt(1/3)
    const int j = tid;
    const float mterm = INF_ * (mask[i] * mask[j] - 1.0f);
    #pragma unroll 1
    for (int h = 0; h < NH; h++) {
        float qk = 0.0f;
        #pragma unroll
        for (int c = 0; c < 16; c++)
            qk += qrow[h * 16 + c] * KT[(h * 16 + c) * NTOK + j];
        float pt = 0.0f;
        #pragma unroll
        for (int d = 0; d < 12; d++) {
            const float dv = qprow[h * 12 + d] - KPT[(h * 12 + d) * NTOK + j];
            pt += dv * dv;
        }
        LB[h][j] = qk * qk_scale + b_scale * BBT[((size_t)i * 12 + h) * NTOK + j]
                 - 0.5f * hwL[h] * pt + mterm;
    }
    __syncthreads();

    // softmax: wave w handles head w (12 waves exactly)
    {
        const int h = tid >> 6, lane = tid & 63;
        float m = -3.0e38f;
        for (int jj = lane; jj < NTOK; jj += 64) m = fmaxf(m, LB[h][jj]);
        #pragma unroll
        for (int off = 32; off >= 1; off >>= 1) m = fmaxf(m, __shfl_xor(m, off));
        float ssum = 0.0f;
        for (int jj = lane; jj < NTOK; jj += 64) {
            const float e = __expf(LB[h][jj] - m);
            LB[h][jj] = e;
            ssum += e;
        }
        #pragma unroll
        for (int off = 32; off >= 1; off >>= 1) ssum += __shfl_xor(ssum, off);
        const float inv = 1.0f / ssum;
        for (int jj = lane; jj < NTOK; jj += 64) LB[h][jj] *= inv;
    }
    __syncthreads();

    // weighted sums: per head 16 (o) + 24 (o_pt) + 16 (o_pair bf16x2) = 56 items
    if (tid < 672) {
        const int h = tid / 56, r = tid % 56;
        if (r < 40) {
            const float4* s4 = (r < 16) ? (const float4*)&VT[(h * 16 + r) * NTOK]
                                        : (const float4*)&VPT[(h * 24 + (r - 16)) * NTOK];
            const float4* a4 = (const float4*)&LB[h][0];
            float acc = 0.0f;
            for (int j4 = 0; j4 < NTOK / 4; j4++) {
                const float4 a = a4[j4], v = s4[j4];
                acc += a.x * v.x + a.y * v.y + a.z * v.z + a.w * v.w;
            }
            if (r < 16) O[i * 192 + h * 16 + r] = acc;
            else        OPT[i * 288 + h * 24 + (r - 16)] = acc;
        } else {
            const int c2 = r - 40;
            const uint32* pzr = (const uint32*)(PZT + (size_t)i * NTOK * 32);
            float a0 = 0.0f, a1 = 0.0f;
            for (int jj = 0; jj < NTOK; jj++) {
                const uint32 u = pzr[jj * 16 + c2];
                const float p = LB[h][jj];
                a0 += p * bflo(u);
                a1 += p * bfhi(u);
            }
            OPAIR[i * 384 + h * 32 + 2 * c2]     = a0;
            OPAIR[i * 384 + h * 32 + 2 * c2 + 1] = a1;
        }
    }
}

// ---------------------------------------------------------------------------
// K4: inverse rotation + norms + concat + final linear (8 tokens/block)
// ---------------------------------------------------------------------------
#define K4T 8
__global__ __launch_bounds__(256) void k4_out(
    const float* __restrict__ O, const float* __restrict__ OPT, const float* __restrict__ OPAIR,
    const float* __restrict__ rot, const float* __restrict__ trans,
    const float* __restrict__ wout, const float* __restrict__ bout,
    float* __restrict__ out)
{
    __shared__ float f[K4T][960];
    const int n0 = blockIdx.x * K4T, tid = threadIdx.x;

    for (int idx = tid; idx < K4T * 192; idx += 256) {
        const int t = idx / 192, k = idx % 192;
        f[t][k] = O[(n0 + t) * 192 + k];
    }
    for (int idx = tid; idx < K4T * 384; idx += 256) {
        const int t = idx / 384, k = idx % 384;
        f[t][576 + k] = OPAIR[(n0 + t) * 384 + k];
    }
    for (int idx = tid; idx < K4T * 96; idx += 256) {
        const int t = idx / 96, hp = idx % 96;
        const int n = n0 + t;
        const float vx = OPT[n * 288 + hp * 3 + 0] - trans[n * 3 + 0];
        const float vy = OPT[n * 288 + hp * 3 + 1] - trans[n * 3 + 1];
        const float vz = OPT[n * 288 + hp * 3 + 2] - trans[n * 3 + 2];
        const float o0 = rot[n*9+0]*vx + rot[n*9+3]*vy + rot[n*9+6]*vz;
        const float o1 = rot[n*9+1]*vx + rot[n*9+4]*vy + rot[n*9+7]*vz;
        const float o2 = rot[n*9+2]*vx + rot[n*9+5]*vy + rot[n*9+8]*vz;
        f[t][192 + hp] = o0;
        f[t][288 + hp] = o1;
        f[t][384 + hp] = o2;
        f[t][480 + hp] = sqrtf(o0*o0 + o1*o1 + o2*o2 + EPS_);
    }
    __syncthreads();

    for (int o = tid; o < 384; o += 256) {
        float acc[K4T];
        #pragma unroll
        for (int t = 0; t < K4T; t++) acc[t] = bout[o];
        for (int k = 0; k < 960; k++) {
            const float wv = wout[k * 384 + o];
            #pragma unroll
            for (int t = 0; t < K4T; t++) acc[t] += f[t][k] * wv;
        }
        #pragma unroll
        for (int t = 0; t < K4T; t++) out[(n0 + t) * 384 + o] = acc[t];
    }
}

// ---------------------------------------------------------------------------
extern "C" void kernel_launch(void* const* d_in, const int* in_sizes, int n_in,
                              void* d_out, int out_size, void* d_ws, size_t ws_size,
                              hipStream_t stream) {
    (void)in_sizes; (void)n_in; (void)out_size; (void)ws_size;
    const float* s     = (const float*)d_in[0];
    const float* z     = (const float*)d_in[1];
    const float* rot   = (const float*)d_in[2];
    const float* trans = (const float*)d_in[3];
    const float* mask  = (const float*)d_in[4];
    const float* wq    = (const float*)d_in[5];
    const float* bq    = (const float*)d_in[6];
    const float* wkv   = (const float*)d_in[7];
    const float* bkv   = (const float*)d_in[8];
    const float* wqp   = (const float*)d_in[9];
    const float* bqp   = (const float*)d_in[10];
    const float* wkvp  = (const float*)d_in[11];
    const float* bkvp  = (const float*)d_in[12];
    const float* wb    = (const float*)d_in[13];
    const float* bb    = (const float*)d_in[14];
    const float* wdz   = (const float*)d_in[15];
    const float* bdz   = (const float*)d_in[16];
    const float* hwts  = (const float*)d_in[17];
    const float* wout  = (const float*)d_in[18];
    const float* bout  = (const float*)d_in[19];
    float* out = (float*)d_out;

    float* ws = (float*)d_ws;
    float* Q     = ws;                       // 147456
    float* KT    = Q     + 147456;           // 147456
    float* VT    = KT    + 147456;           // 147456
    float* QP    = VT    + 147456;           // 110592
    float* KPT   = QP    + 110592;           // 110592
    float* VPT   = KPT   + 110592;           // 221184
    float* O     = VPT   + 221184;           // 147456
    float* OPT   = O     + 147456;           // 221184
    float* OPAIR = OPT   + 221184;           // 294912
    float* BBT   = OPAIR + 294912;           // 7,077,888 floats (28.3 MB)
    ushort16* PZT = (ushort16*)(BBT + 7077888); // 768*768*32 bf16 (37.7 MB)
    // total ws: ~72.2 MB

    hipLaunchKernelGGL(k1_proj, dim3(NTOK / K1T), dim3(256), 0, stream,
                       s, rot, trans, wq, bq, wkv, bkv, wqp, bqp, wkvp, bkvp,
                       Q, KT, VT, QP, KPT, VPT);
    hipLaunchKernelGGL(k2_zproj, dim3(3, NTOK), dim3(256), 0, stream,
                       z, wb, bb, wdz, bdz, BBT, PZT);
    hipLaunchKernelGGL(k3_attn, dim3(NTOK), dim3(768), 0, stream,
                       KT, VT, KPT, VPT, Q, QP, BBT, PZT, mask, hwts,
                       O, OPT, OPAIR);
    hipLaunchKernelGGL(k4_out, dim3(NTOK / K4T), dim3(256), 0, stream,
                       O, OPT, OPAIR, rot, trans, wout, bout, out);
}

// Round 6
// 1573.158 us; speedup vs baseline: 5.1236x; 5.1236x over previous
//
#include <hip/hip_runtime.h>
#include <math.h>

#define NTOK 768
#define CS   384
#define CZ   128
#define NH   12
#define INF_ 100000.0f
#define EPS_ 1e-8f

typedef unsigned int  uint32;
typedef unsigned short ushort16;

__device__ __forceinline__ uint32 bf16rn(float x) {
    uint32 u = __float_as_uint(x);
    return (u + 0x7fffu + ((u >> 16) & 1u)) >> 16;
}
__device__ __forceinline__ float bflo(uint32 u) { return __uint_as_float((u & 0xffffu) << 16); }
__device__ __forceinline__ float bfhi(uint32 u) { return __uint_as_float(u & 0xffff0000u); }

// ---------------------------------------------------------------------------
// K1: s-projections + rigid transform. 4 tokens/block to amortize weight reads.
// ---------------------------------------------------------------------------
#define K1T 4
__global__ __launch_bounds__(256) void k1_proj(
    const float* __restrict__ s, const float* __restrict__ rot, const float* __restrict__ trans,
    const float* __restrict__ wq, const float* __restrict__ bq,
    const float* __restrict__ wkv, const float* __restrict__ bkv,
    const float* __restrict__ wqp, const float* __restrict__ bqp,
    const float* __restrict__ wkvp, const float* __restrict__ bkvp,
    float* __restrict__ Q, float* __restrict__ KT, float* __restrict__ VT,
    float* __restrict__ QP, float* __restrict__ KPT, float* __restrict__ VPT)
{
    __shared__ float sL[K1T][CS];
    __shared__ float rotL[K1T][9], transL[K1T][3];
    const int n0 = blockIdx.x * K1T, tid = threadIdx.x;

    for (int idx = tid; idx < K1T * CS; idx += 256) {
        const int t = idx / CS, k = idx % CS;
        sL[t][k] = s[(n0 + t) * CS + k];
    }
    if (tid < K1T * 9)  rotL[tid / 9][tid % 9] = rot[n0 * 9 + tid];
    if (tid >= 64 && tid < 64 + K1T * 3) {
        const int q = tid - 64;
        transL[q / 3][q % 3] = trans[n0 * 3 + q];
    }
    __syncthreads();

    for (int item = tid; item < 768; item += 256) {
        if (item < 192) {                       // q
            const int col = item;
            float acc[K1T];
            #pragma unroll
            for (int t = 0; t < K1T; t++) acc[t] = bq[col];
            for (int k = 0; k < CS; k++) {
                const float w = wq[k * 192 + col];
                #pragma unroll
                for (int t = 0; t < K1T; t++) acc[t] += sL[t][k] * w;
            }
            #pragma unroll
            for (int t = 0; t < K1T; t++) Q[(n0 + t) * 192 + col] = acc[t];
        } else if (item < 576) {                // k, v (kv cols: h*32 + [0..15]=k, [16..31]=v)
            const int r = item - 192;
            const bool isV = (r >= 192);
            const int idx = isV ? r - 192 : r;  // h*16+c
            const int h = idx >> 4, c = idx & 15;
            const int col = h * 32 + (isV ? 16 : 0) + c;
            float acc[K1T];
            #pragma unroll
            for (int t = 0; t < K1T; t++) acc[t] = bkv[col];
            for (int k = 0; k < CS; k++) {
                const float w = wkv[k * 384 + col];
                #pragma unroll
                for (int t = 0; t < K1T; t++) acc[t] += sL[t][k] * w;
            }
            #pragma unroll
            for (int t = 0; t < K1T; t++) {
                if (isV) VT[idx * NTOK + (n0 + t)] = acc[t];
                else     KT[idx * NTOK + (n0 + t)] = acc[t];
            }
        } else if (item < 624) {                // q points: pidx = h*4+p in [0,48)
            const int pidx = item - 576;
            float raw[K1T][3];
            #pragma unroll
            for (int x = 0; x < 3; x++) {
                const int col = x * 48 + pidx;
                float acc[K1T];
                #pragma unroll
                for (int t = 0; t < K1T; t++) acc[t] = bqp[col];
                for (int k = 0; k < CS; k++) {
                    const float w = wqp[k * 144 + col];
                    #pragma unroll
                    for (int t = 0; t < K1T; t++) acc[t] += sL[t][k] * w;
                }
                #pragma unroll
                for (int t = 0; t < K1T; t++) raw[t][x] = acc[t];
            }
            #pragma unroll
            for (int t = 0; t < K1T; t++)
                #pragma unroll
                for (int x = 0; x < 3; x++) {
                    const float v = rotL[t][x*3+0]*raw[t][0] + rotL[t][x*3+1]*raw[t][1]
                                  + rotL[t][x*3+2]*raw[t][2] + transL[t][x];
                    QP[(n0 + t) * 144 + pidx * 3 + x] = v;
                }
        } else {                                // kv points: pidx = h*12+pp in [0,144)
            const int pidx = item - 624;
            float raw[K1T][3];
            #pragma unroll
            for (int x = 0; x < 3; x++) {
                const int col = x * 144 + pidx;
                float acc[K1T];
                #pragma unroll
                for (int t = 0; t < K1T; t++) acc[t] = bkvp[col];
                for (int k = 0; k < CS; k++) {
                    const float w = wkvp[k * 432 + col];
                    #pragma unroll
                    for (int t = 0; t < K1T; t++) acc[t] += sL[t][k] * w;
                }
                #pragma unroll
                for (int t = 0; t < K1T; t++) raw[t][x] = acc[t];
            }
            const int h = pidx / 12, pp = pidx % 12;
            #pragma unroll
            for (int t = 0; t < K1T; t++)
                #pragma unroll
                for (int x = 0; x < 3; x++) {
                    const float v = rotL[t][x*3+0]*raw[t][0] + rotL[t][x*3+1]*raw[t][1]
                                  + rotL[t][x*3+2]*raw[t][2] + transL[t][x];
                    if (pp < 4) KPT[((h * 4 + pp) * 3 + x) * NTOK + (n0 + t)] = v;
                    else        VPT[((h * 8 + (pp - 4)) * 3 + x) * NTOK + (n0 + t)] = v;
                }
        }
    }
}

// ---------------------------------------------------------------------------
// K2: z projections, streaming. BBT[i][h][j] f32; PZT[i][j][c] bf16 (packed).
// grid (3, 768): by=i, j = bx*256+tid.
// NO min-occupancy bound: acc[44] + unrolled loads need ~100 VGPR; forcing
// occupancy spilled acc to scratch (24.5 GB HBM traffic in round 5).
// ---------------------------------------------------------------------------
__global__ __launch_bounds__(256) void k2_zproj(
    const float* __restrict__ z, const float* __restrict__ wb, const float* __restrict__ bb,
    const float* __restrict__ wdz, const float* __restrict__ bdz,
    float* __restrict__ BBT, ushort16* __restrict__ PZT)
{
    __shared__ float wL[CZ * 44];     // [k][44]: o<12 -> wb, else wdz
    __shared__ float biasL[44];
    const int tid = threadIdx.x;
    for (int idx = tid; idx < CZ * 44; idx += 256) {
        const int k = idx / 44, o = idx % 44;
        wL[idx] = (o < 12) ? wb[k * 12 + o] : wdz[k * 32 + (o - 12)];
    }
    if (tid < 44) biasL[tid] = (tid < 12) ? bb[tid] : bdz[tid - 12];
    __syncthreads();

    const int i = blockIdx.y;
    const int j = blockIdx.x * 256 + tid;
    const float4* zrow = (const float4*)(z + ((size_t)i * NTOK + j) * CZ);

    float acc[44];
    #pragma unroll
    for (int o = 0; o < 44; o++) acc[o] = biasL[o];

    #pragma unroll 4
    for (int k4 = 0; k4 < CZ / 4; k4++) {
        const float4 zv = zrow[k4];
        const float* w0 = &wL[(k4 * 4) * 44];
        #pragma unroll
        for (int o = 0; o < 44; o++)
            acc[o] += zv.x * w0[o] + zv.y * w0[o + 44] + zv.z * w0[o + 88] + zv.w * w0[o + 132];
    }

    #pragma unroll
    for (int h = 0; h < 12; h++) BBT[((size_t)i * 12 + h) * NTOK + j] = acc[h];

    uint32 pk[16];
    #pragma unroll
    for (int c2 = 0; c2 < 16; c2++)
        pk[c2] = bf16rn(acc[12 + 2 * c2]) | (bf16rn(acc[12 + 2 * c2 + 1]) << 16);
    uint4* dst = (uint4*)(PZT + ((size_t)i * NTOK + j) * 32);   // 64B/thread, coalesced
    dst[0] = make_uint4(pk[0],  pk[1],  pk[2],  pk[3]);
    dst[1] = make_uint4(pk[4],  pk[5],  pk[6],  pk[7]);
    dst[2] = make_uint4(pk[8],  pk[9],  pk[10], pk[11]);
    dst[3] = make_uint4(pk[12], pk[13], pk[14], pk[15]);
}

// ---------------------------------------------------------------------------
// K3: attention per row i. LDS ~37.5 KB; no register cap (no spill risk).
// ---------------------------------------------------------------------------
__global__ __launch_bounds__(768) void k3_attn(
    const float* __restrict__ KT, const float* __restrict__ VT,
    const float* __restrict__ KPT, const float* __restrict__ VPT,
    const float* __restrict__ Q, const float* __restrict__ QP,
    const float* __restrict__ BBT, const ushort16* __restrict__ PZT,
    const float* __restrict__ mask, const float* __restrict__ head_weights,
    float* __restrict__ O, float* __restrict__ OPT, float* __restrict__ OPAIR)
{
    __shared__ float LB[NH][NTOK];      // logits -> probs in place
    __shared__ float qrow[192], qprow[144], hwL[NH];
    const int i = blockIdx.x, tid = threadIdx.x;

    if (tid < 192) qrow[tid] = Q[i * 192 + tid];
    else if (tid >= 256 && tid < 400) qprow[tid - 256] = QP[i * 144 + (tid - 256)];
    else if (tid >= 448 && tid < 460)
        hwL[tid - 448] = logf(1.0f + expf(head_weights[tid - 448])) * 0.13608276348795434f; // sqrt(1/54)
    __syncthreads();

    const float qk_scale = 0.14433756729740643f;   // sqrt(1/48)
    const float b_scale  = 0.5773502691896258f;    // sqrt(1/3)
    const int j = tid;
    const float mterm = INF_ * (mask[i] * mask[j] - 1.0f);
    #pragma unroll 1
    for (int h = 0; h < NH; h++) {
        float qk = 0.0f;
        #pragma unroll
        for (int c = 0; c < 16; c++)
            qk += qrow[h * 16 + c] * KT[(h * 16 + c) * NTOK + j];
        float pt = 0.0f;
        #pragma unroll
        for (int d = 0; d < 12; d++) {
            const float dv = qprow[h * 12 + d] - KPT[(h * 12 + d) * NTOK + j];
            pt += dv * dv;
        }
        LB[h][j] = qk * qk_scale + b_scale * BBT[((size_t)i * 12 + h) * NTOK + j]
                 - 0.5f * hwL[h] * pt + mterm;
    }
    __syncthreads();

    // softmax: wave w handles head w (12 waves exactly)
    {
        const int h = tid >> 6, lane = tid & 63;
        float m = -3.0e38f;
        for (int jj = lane; jj < NTOK; jj += 64) m = fmaxf(m, LB[h][jj]);
        #pragma unroll
        for (int off = 32; off >= 1; off >>= 1) m = fmaxf(m, __shfl_xor(m, off));
        float ssum = 0.0f;
        for (int jj = lane; jj < NTOK; jj += 64) {
            const float e = __expf(LB[h][jj] - m);
            LB[h][jj] = e;
            ssum += e;
        }
        #pragma unroll
        for (int off = 32; off >= 1; off >>= 1) ssum += __shfl_xor(ssum, off);
        const float inv = 1.0f / ssum;
        for (int jj = lane; jj < NTOK; jj += 64) LB[h][jj] *= inv;
    }
    __syncthreads();

    // weighted sums: per head 16 (o) + 24 (o_pt) + 16 (o_pair bf16x2) = 56 items
    if (tid < 672) {
        const int h = tid / 56, r = tid % 56;
        if (r < 40) {
            const float4* s4 = (r < 16) ? (const float4*)&VT[(h * 16 + r) * NTOK]
                                        : (const float4*)&VPT[(h * 24 + (r - 16)) * NTOK];
            const float4* a4 = (const float4*)&LB[h][0];
            float acc = 0.0f;
            for (int j4 = 0; j4 < NTOK / 4; j4++) {
                const float4 a = a4[j4], v = s4[j4];
                acc += a.x * v.x + a.y * v.y + a.z * v.z + a.w * v.w;
            }
            if (r < 16) O[i * 192 + h * 16 + r] = acc;
            else        OPT[i * 288 + h * 24 + (r - 16)] = acc;
        } else {
            const int c2 = r - 40;
            const uint32* pzr = (const uint32*)(PZT + (size_t)i * NTOK * 32);
            float a0 = 0.0f, a1 = 0.0f;
            for (int jj = 0; jj < NTOK; jj++) {
                const uint32 u = pzr[jj * 16 + c2];
                const float p = LB[h][jj];
                a0 += p * bflo(u);
                a1 += p * bfhi(u);
            }
            OPAIR[i * 384 + h * 32 + 2 * c2]     = a0;
            OPAIR[i * 384 + h * 32 + 2 * c2 + 1] = a1;
        }
    }
}

// ---------------------------------------------------------------------------
// K4: inverse rotation + norms + concat + final linear (8 tokens/block)
// ---------------------------------------------------------------------------
#define K4T 8
__global__ __launch_bounds__(256) void k4_out(
    const float* __restrict__ O, const float* __restrict__ OPT, const float* __restrict__ OPAIR,
    const float* __restrict__ rot, const float* __restrict__ trans,
    const float* __restrict__ wout, const float* __restrict__ bout,
    float* __restrict__ out)
{
    __shared__ float f[K4T][960];
    const int n0 = blockIdx.x * K4T, tid = threadIdx.x;

    for (int idx = tid; idx < K4T * 192; idx += 256) {
        const int t = idx / 192, k = idx % 192;
        f[t][k] = O[(n0 + t) * 192 + k];
    }
    for (int idx = tid; idx < K4T * 384; idx += 256) {
        const int t = idx / 384, k = idx % 384;
        f[t][576 + k] = OPAIR[(n0 + t) * 384 + k];
    }
    for (int idx = tid; idx < K4T * 96; idx += 256) {
        const int t = idx / 96, hp = idx % 96;
        const int n = n0 + t;
        const float vx = OPT[n * 288 + hp * 3 + 0] - trans[n * 3 + 0];
        const float vy = OPT[n * 288 + hp * 3 + 1] - trans[n * 3 + 1];
        const float vz = OPT[n * 288 + hp * 3 + 2] - trans[n * 3 + 2];
        const float o0 = rot[n*9+0]*vx + rot[n*9+3]*vy + rot[n*9+6]*vz;
        const float o1 = rot[n*9+1]*vx + rot[n*9+4]*vy + rot[n*9+7]*vz;
        const float o2 = rot[n*9+2]*vx + rot[n*9+5]*vy + rot[n*9+8]*vz;
        f[t][192 + hp] = o0;
        f[t][288 + hp] = o1;
        f[t][384 + hp] = o2;
        f[t][480 + hp] = sqrtf(o0*o0 + o1*o1 + o2*o2 + EPS_);
    }
    __syncthreads();

    for (int o = tid; o < 384; o += 256) {
        float acc[K4T];
        #pragma unroll
        for (int t = 0; t < K4T; t++) acc[t] = bout[o];
        for (int k = 0; k < 960; k++) {
            const float wv = wout[k * 384 + o];
            #pragma unroll
            for (int t = 0; t < K4T; t++) acc[t] += f[t][k] * wv;
        }
        #pragma unroll
        for (int t = 0; t < K4T; t++) out[(n0 + t) * 384 + o] = acc[t];
    }
}

// ---------------------------------------------------------------------------
extern "C" void kernel_launch(void* const* d_in, const int* in_sizes, int n_in,
                              void* d_out, int out_size, void* d_ws, size_t ws_size,
                              hipStream_t stream) {
    (void)in_sizes; (void)n_in; (void)out_size; (void)ws_size;
    const float* s     = (const float*)d_in[0];
    const float* z     = (const float*)d_in[1];
    const float* rot   = (const float*)d_in[2];
    const float* trans = (const float*)d_in[3];
    const float* mask  = (const float*)d_in[4];
    const float* wq    = (const float*)d_in[5];
    const float* bq    = (const float*)d_in[6];
    const float* wkv   = (const float*)d_in[7];
    const float* bkv   = (const float*)d_in[8];
    const float* wqp   = (const float*)d_in[9];
    const float* bqp   = (const float*)d_in[10];
    const float* wkvp  = (const float*)d_in[11];
    const float* bkvp  = (const float*)d_in[12];
    const float* wb    = (const float*)d_in[13];
    const float* bb    = (const float*)d_in[14];
    const float* wdz   = (const float*)d_in[15];
    const float* bdz   = (const float*)d_in[16];
    const float* hwts  = (const float*)d_in[17];
    const float* wout  = (const float*)d_in[18];
    const float* bout  = (const float*)d_in[19];
    float* out = (float*)d_out;

    float* ws = (float*)d_ws;
    float* Q     = ws;                       // 147456
    float* KT    = Q     + 147456;           // 147456
    float* VT    = KT    + 147456;           // 147456
    float* QP    = VT    + 147456;           // 110592
    float* KPT   = QP    + 110592;           // 110592
    float* VPT   = KPT   + 110592;           // 221184
    float* O     = VPT   + 221184;           // 147456
    float* OPT   = O     + 147456;           // 221184
    float* OPAIR = OPT   + 221184;           // 294912
    float* BBT   = OPAIR + 294912;           // 7,077,888 floats (28.3 MB)
    ushort16* PZT = (ushort16*)(BBT + 7077888); // 768*768*32 bf16 (37.7 MB)
    // total ws: ~72.2 MB

    hipLaunchKernelGGL(k1_proj, dim3(NTOK / K1T), dim3(256), 0, stream,
                       s, rot, trans, wq, bq, wkv, bkv, wqp, bqp, wkvp, bkvp,
                       Q, KT, VT, QP, KPT, VPT);
    hipLaunchKernelGGL(k2_zproj, dim3(3, NTOK), dim3(256), 0, stream,
                       z, wb, bb, wdz, bdz, BBT, PZT);
    hipLaunchKernelGGL(k3_attn, dim3(NTOK), dim3(768), 0, stream,
                       KT, VT, KPT, VPT, Q, QP, BBT, PZT, mask, hwts,
                       O, OPT, OPAIR);
    hipLaunchKernelGGL(k4_out, dim3(NTOK / K4T), dim3(256), 0, stream,
                       O, OPT, OPAIR, rot, trans, wout, bout, out);
}

// Round 7
// 629.111 us; speedup vs baseline: 12.8122x; 2.5006x over previous
//
#include <hip/hip_runtime.h>
#include <math.h>

#define NTOK 768
#define CS   384
#define CZ   128
#define NH   12
#define INF_ 100000.0f
#define EPS_ 1e-8f

typedef unsigned int  uint32;
typedef unsigned short ushort16;

__device__ __forceinline__ uint32 bf16rn(float x) {
    uint32 u = __float_as_uint(x);
    return (u + 0x7fffu + ((u >> 16) & 1u)) >> 16;
}
__device__ __forceinline__ float bflo(uint32 u) { return __uint_as_float((u & 0xffffu) << 16); }
__device__ __forceinline__ float bfhi(uint32 u) { return __uint_as_float(u & 0xffff0000u); }

// ---------------------------------------------------------------------------
// K1a: tiled GEMM. RAW[col][tok] = sum_k s[tok][k] * Wcat[k][col]  (no bias).
// Wcat columns: [0,192)=wq | [192,576)=wkv | [576,720)=wqp | [720,1152)=wkvp.
// Tiles 64x64x32, 256 threads, each computes 4 cols x 4 toks.
// ---------------------------------------------------------------------------
__global__ __launch_bounds__(256) void k1a_gemm(
    const float* __restrict__ s,
    const float* __restrict__ wq, const float* __restrict__ wkv,
    const float* __restrict__ wqp, const float* __restrict__ wkvp,
    float* __restrict__ RAW)
{
    __shared__ float sA[32][72];   // [k][m]  (72 pad: 288B rows, 16B-aligned)
    __shared__ float sB[32][72];   // [k][n]
    const int tid  = threadIdx.x;
    const int tok0 = blockIdx.x * 64;
    const int col0 = blockIdx.y * 64;

    const int m0 = (tid & 15) * 4;
    const int n0 = (tid >> 4) * 4;

    float4 acc[4];
    #pragma unroll
    for (int nn = 0; nn < 4; nn++) acc[nn] = make_float4(0.f, 0.f, 0.f, 0.f);

    // A loader: m = tid/4, k-group = (tid%4)*8  (8 contiguous k, transposed store)
    const int lam = tid >> 2, lak = (tid & 3) * 8;
    // B loader: k = tid/8, col-group = (tid%8)*8 (8 contiguous cols; boundaries
    // 192/576/720 are all multiples of 8 -> group never straddles arrays)
    const int lbk = tid >> 3, lbc = (tid & 7) * 8;
    const int gcol = col0 + lbc;
    const float* wsrc; int wwidth, woff;
    if (gcol < 192)      { wsrc = wq;   wwidth = 192; woff = gcol; }
    else if (gcol < 576) { wsrc = wkv;  wwidth = 384; woff = gcol - 192; }
    else if (gcol < 720) { wsrc = wqp;  wwidth = 144; woff = gcol - 576; }
    else                 { wsrc = wkvp; wwidth = 432; woff = gcol - 720; }

    for (int kb = 0; kb < CS; kb += 32) {
        const float4 a0 = *(const float4*)&s[(tok0 + lam) * CS + kb + lak];
        const float4 a1 = *(const float4*)&s[(tok0 + lam) * CS + kb + lak + 4];
        const float4 b0 = *(const float4*)&wsrc[(size_t)(kb + lbk) * wwidth + woff];
        const float4 b1 = *(const float4*)&wsrc[(size_t)(kb + lbk) * wwidth + woff + 4];
        __syncthreads();
        sA[lak + 0][lam] = a0.x; sA[lak + 1][lam] = a0.y;
        sA[lak + 2][lam] = a0.z; sA[lak + 3][lam] = a0.w;
        sA[lak + 4][lam] = a1.x; sA[lak + 5][lam] = a1.y;
        sA[lak + 6][lam] = a1.z; sA[lak + 7][lam] = a1.w;
        *(float4*)&sB[lbk][lbc]     = b0;
        *(float4*)&sB[lbk][lbc + 4] = b1;
        __syncthreads();
        #pragma unroll
        for (int k = 0; k < 32; k++) {
            const float4 av = *(const float4*)&sA[k][m0];
            const float4 bv = *(const float4*)&sB[k][n0];
            acc[0].x += av.x * bv.x; acc[0].y += av.y * bv.x; acc[0].z += av.z * bv.x; acc[0].w += av.w * bv.x;
            acc[1].x += av.x * bv.y; acc[1].y += av.y * bv.y; acc[1].z += av.z * bv.y; acc[1].w += av.w * bv.y;
            acc[2].x += av.x * bv.z; acc[2].y += av.y * bv.z; acc[2].z += av.z * bv.z; acc[2].w += av.w * bv.z;
            acc[3].x += av.x * bv.w; acc[3].y += av.y * bv.w; acc[3].z += av.z * bv.w; acc[3].w += av.w * bv.w;
        }
    }
    #pragma unroll
    for (int nn = 0; nn < 4; nn++)
        *(float4*)&RAW[(size_t)(col0 + n0 + nn) * NTOK + tok0 + m0] = acc[nn];
}

// ---------------------------------------------------------------------------
// K1b: bias + layout + rigid transform. 16 tokens/block, lane=token (coalesced).
// ---------------------------------------------------------------------------
__global__ __launch_bounds__(256) void k1b_finish(
    const float* __restrict__ RAW,
    const float* __restrict__ rot, const float* __restrict__ trans,
    const float* __restrict__ bq, const float* __restrict__ bkv,
    const float* __restrict__ bqp, const float* __restrict__ bkvp,
    float* __restrict__ Q, float* __restrict__ KT, float* __restrict__ VT,
    float* __restrict__ QP, float* __restrict__ KPT, float* __restrict__ VPT)
{
    const int tid = threadIdx.x;
    const int t  = blockIdx.x * 16 + (tid & 15);
    const int wk = tid >> 4;                      // 16 walkers

    float R[9], T3[3];
    #pragma unroll
    for (int x = 0; x < 9; x++) R[x] = rot[t * 9 + x];
    #pragma unroll
    for (int x = 0; x < 3; x++) T3[x] = trans[t * 3 + x];

    for (int col = wk; col < 192; col += 16)
        Q[t * 192 + col] = RAW[(size_t)col * NTOK + t] + bq[col];

    for (int idx = wk; idx < 192; idx += 16) {
        const int h = idx >> 4, c = idx & 15;
        KT[idx * NTOK + t] = RAW[(size_t)(192 + h * 32 + c)      * NTOK + t] + bkv[h * 32 + c];
        VT[idx * NTOK + t] = RAW[(size_t)(192 + h * 32 + 16 + c) * NTOK + t] + bkv[h * 32 + 16 + c];
    }

    for (int pidx = wk; pidx < 48; pidx += 16) {
        const float r0 = RAW[(size_t)(576 + 0 * 48 + pidx) * NTOK + t] + bqp[0 * 48 + pidx];
        const float r1 = RAW[(size_t)(576 + 1 * 48 + pidx) * NTOK + t] + bqp[1 * 48 + pidx];
        const float r2 = RAW[(size_t)(576 + 2 * 48 + pidx) * NTOK + t] + bqp[2 * 48 + pidx];
        #pragma unroll
        for (int x = 0; x < 3; x++)
            QP[t * 144 + pidx * 3 + x] = R[x*3+0]*r0 + R[x*3+1]*r1 + R[x*3+2]*r2 + T3[x];
    }

    for (int pidx = wk; pidx < 144; pidx += 16) {
        const float r0 = RAW[(size_t)(720 + 0 * 144 + pidx) * NTOK + t] + bkvp[0 * 144 + pidx];
        const float r1 = RAW[(size_t)(720 + 1 * 144 + pidx) * NTOK + t] + bkvp[1 * 144 + pidx];
        const float r2 = RAW[(size_t)(720 + 2 * 144 + pidx) * NTOK + t] + bkvp[2 * 144 + pidx];
        const int h = pidx / 12, pp = pidx % 12;
        #pragma unroll
        for (int x = 0; x < 3; x++) {
            const float v = R[x*3+0]*r0 + R[x*3+1]*r1 + R[x*3+2]*r2 + T3[x];
            if (pp < 4) KPT[((h * 4 + pp)  * 3 + x) * NTOK + t] = v;
            else        VPT[((h * 8 + pp - 4) * 3 + x) * NTOK + t] = v;
        }
    }
}

// ---------------------------------------------------------------------------
// K2: z projections, streaming. BBT[i][h][j] f32; PZT[i][j][c] bf16 (packed).
// NO min-occupancy bound: acc[44] needs ~100 VGPR; forcing occupancy spilled
// acc to scratch (24.5 GB HBM traffic in round 5).
// ---------------------------------------------------------------------------
__global__ __launch_bounds__(256) void k2_zproj(
    const float* __restrict__ z, const float* __restrict__ wb, const float* __restrict__ bb,
    const float* __restrict__ wdz, const float* __restrict__ bdz,
    float* __restrict__ BBT, ushort16* __restrict__ PZT)
{
    __shared__ float wL[CZ * 44];     // [k][44]: o<12 -> wb, else wdz
    __shared__ float biasL[44];
    const int tid = threadIdx.x;
    for (int idx = tid; idx < CZ * 44; idx += 256) {
        const int k = idx / 44, o = idx % 44;
        wL[idx] = (o < 12) ? wb[k * 12 + o] : wdz[k * 32 + (o - 12)];
    }
    if (tid < 44) biasL[tid] = (tid < 12) ? bb[tid] : bdz[tid - 12];
    __syncthreads();

    const int i = blockIdx.y;
    const int j = blockIdx.x * 256 + tid;
    const float4* zrow = (const float4*)(z + ((size_t)i * NTOK + j) * CZ);

    float acc[44];
    #pragma unroll
    for (int o = 0; o < 44; o++) acc[o] = biasL[o];

    #pragma unroll 4
    for (int k4 = 0; k4 < CZ / 4; k4++) {
        const float4 zv = zrow[k4];
        const float* w0 = &wL[(k4 * 4) * 44];
        #pragma unroll
        for (int o = 0; o < 44; o++)
            acc[o] += zv.x * w0[o] + zv.y * w0[o + 44] + zv.z * w0[o + 88] + zv.w * w0[o + 132];
    }

    #pragma unroll
    for (int h = 0; h < 12; h++) BBT[((size_t)i * 12 + h) * NTOK + j] = acc[h];

    uint32 pk[16];
    #pragma unroll
    for (int c2 = 0; c2 < 16; c2++)
        pk[c2] = bf16rn(acc[12 + 2 * c2]) | (bf16rn(acc[12 + 2 * c2 + 1]) << 16);
    uint4* dst = (uint4*)(PZT + ((size_t)i * NTOK + j) * 32);   // 64B/thread, coalesced
    dst[0] = make_uint4(pk[0],  pk[1],  pk[2],  pk[3]);
    dst[1] = make_uint4(pk[4],  pk[5],  pk[6],  pk[7]);
    dst[2] = make_uint4(pk[8],  pk[9],  pk[10], pk[11]);
    dst[3] = make_uint4(pk[12], pk[13], pk[14], pk[15]);
}

// ---------------------------------------------------------------------------
// K3: attention per row i. LDS ~37.5 KB; no register cap.
// ---------------------------------------------------------------------------
__global__ __launch_bounds__(768) void k3_attn(
    const float* __restrict__ KT, const float* __restrict__ VT,
    const float* __restrict__ KPT, const float* __restrict__ VPT,
    const float* __restrict__ Q, const float* __restrict__ QP,
    const float* __restrict__ BBT, const ushort16* __restrict__ PZT,
    const float* __restrict__ mask, const float* __restrict__ head_weights,
    float* __restrict__ O, float* __restrict__ OPT, float* __restrict__ OPAIR)
{
    __shared__ float LB[NH][NTOK];      // logits -> probs in place
    __shared__ float qrow[192], qprow[144], hwL[NH];
    const int i = blockIdx.x, tid = threadIdx.x;

    if (tid < 192) qrow[tid] = Q[i * 192 + tid];
    else if (tid >= 256 && tid < 400) qprow[tid - 256] = QP[i * 144 + (tid - 256)];
    else if (tid >= 448 && tid < 460)
        hwL[tid - 448] = logf(1.0f + expf(head_weights[tid - 448])) * 0.13608276348795434f; // sqrt(1/54)
    __syncthreads();

    const float qk_scale = 0.14433756729740643f;   // sqrt(1/48)
    const float b_scale  = 0.5773502691896258f;    // sqrt(1/3)
    const int j = tid;
    const float mterm = INF_ * (mask[i] * mask[j] - 1.0f);
    #pragma unroll 1
    for (int h = 0; h < NH; h++) {
        float qk = 0.0f;
        #pragma unroll
        for (int c = 0; c < 16; c++)
            qk += qrow[h * 16 + c] * KT[(h * 16 + c) * NTOK + j];
        float pt = 0.0f;
        #pragma unroll
        for (int d = 0; d < 12; d++) {
            const float dv = qprow[h * 12 + d] - KPT[(h * 12 + d) * NTOK + j];
            pt += dv * dv;
        }
        LB[h][j] = qk * qk_scale + b_scale * BBT[((size_t)i * 12 + h) * NTOK + j]
                 - 0.5f * hwL[h] * pt + mterm;
    }
    __syncthreads();

    // softmax: wave w handles head w (12 waves exactly)
    {
        const int h = tid >> 6, lane = tid & 63;
        float m = -3.0e38f;
        for (int jj = lane; jj < NTOK; jj += 64) m = fmaxf(m, LB[h][jj]);
        #pragma unroll
        for (int off = 32; off >= 1; off >>= 1) m = fmaxf(m, __shfl_xor(m, off));
        float ssum = 0.0f;
        for (int jj = lane; jj < NTOK; jj += 64) {
            const float e = __expf(LB[h][jj] - m);
            LB[h][jj] = e;
            ssum += e;
        }
        #pragma unroll
        for (int off = 32; off >= 1; off >>= 1) ssum += __shfl_xor(ssum, off);
        const float inv = 1.0f / ssum;
        for (int jj = lane; jj < NTOK; jj += 64) LB[h][jj] *= inv;
    }
    __syncthreads();

    // weighted sums: per head 16 (o) + 24 (o_pt) + 16 (o_pair bf16x2) = 56 items
    if (tid < 672) {
        const int h = tid / 56, r = tid % 56;
        if (r < 40) {
            const float4* s4 = (r < 16) ? (const float4*)&VT[(h * 16 + r) * NTOK]
                                        : (const float4*)&VPT[(h * 24 + (r - 16)) * NTOK];
            const float4* a4 = (const float4*)&LB[h][0];
            float acc = 0.0f;
            for (int j4 = 0; j4 < NTOK / 4; j4++) {
                const float4 a = a4[j4], v = s4[j4];
                acc += a.x * v.x + a.y * v.y + a.z * v.z + a.w * v.w;
            }
            if (r < 16) O[i * 192 + h * 16 + r] = acc;
            else        OPT[i * 288 + h * 24 + (r - 16)] = acc;
        } else {
            const int c2 = r - 40;
            const uint32* pzr = (const uint32*)(PZT + (size_t)i * NTOK * 32);
            float a0 = 0.0f, a1 = 0.0f;
            for (int jj = 0; jj < NTOK; jj++) {
                const uint32 u = pzr[jj * 16 + c2];
                const float p = LB[h][jj];
                a0 += p * bflo(u);
                a1 += p * bfhi(u);
            }
            OPAIR[i * 384 + h * 32 + 2 * c2]     = a0;
            OPAIR[i * 384 + h * 32 + 2 * c2 + 1] = a1;
        }
    }
}

// ---------------------------------------------------------------------------
// K4: inverse rotation + norms + concat + final linear (8 tokens/block)
// ---------------------------------------------------------------------------
#define K4T 8
__global__ __launch_bounds__(256) void k4_out(
    const float* __restrict__ O, const float* __restrict__ OPT, const float* __restrict__ OPAIR,
    const float* __restrict__ rot, const float* __restrict__ trans,
    const float* __restrict__ wout, const float* __restrict__ bout,
    float* __restrict__ out)
{
    __shared__ float f[K4T][960];
    const int n0 = blockIdx.x * K4T, tid = threadIdx.x;

    for (int idx = tid; idx < K4T * 192; idx += 256) {
        const int t = idx / 192, k = idx % 192;
        f[t][k] = O[(n0 + t) * 192 + k];
    }
    for (int idx = tid; idx < K4T * 384; idx += 256) {
        const int t = idx / 384, k = idx % 384;
        f[t][576 + k] = OPAIR[(n0 + t) * 384 + k];
    }
    for (int idx = tid; idx < K4T * 96; idx += 256) {
        const int t = idx / 96, hp = idx % 96;
        const int n = n0 + t;
        const float vx = OPT[n * 288 + hp * 3 + 0] - trans[n * 3 + 0];
        const float vy = OPT[n * 288 + hp * 3 + 1] - trans[n * 3 + 1];
        const float vz = OPT[n * 288 + hp * 3 + 2] - trans[n * 3 + 2];
        const float o0 = rot[n*9+0]*vx + rot[n*9+3]*vy + rot[n*9+6]*vz;
        const float o1 = rot[n*9+1]*vx + rot[n*9+4]*vy + rot[n*9+7]*vz;
        const float o2 = rot[n*9+2]*vx + rot[n*9+5]*vy + rot[n*9+8]*vz;
        f[t][192 + hp] = o0;
        f[t][288 + hp] = o1;
        f[t][384 + hp] = o2;
        f[t][480 + hp] = sqrtf(o0*o0 + o1*o1 + o2*o2 + EPS_);
    }
    __syncthreads();

    for (int o = tid; o < 384; o += 256) {
        float acc[K4T];
        #pragma unroll
        for (int t = 0; t < K4T; t++) acc[t] = bout[o];
        for (int k = 0; k < 960; k++) {
            const float wv = wout[k * 384 + o];
            #pragma unroll
            for (int t = 0; t < K4T; t++) acc[t] += f[t][k] * wv;
        }
        #pragma unroll
        for (int t = 0; t < K4T; t++) out[(n0 + t) * 384 + o] = acc[t];
    }
}

// ---------------------------------------------------------------------------
extern "C" void kernel_launch(void* const* d_in, const int* in_sizes, int n_in,
                              void* d_out, int out_size, void* d_ws, size_t ws_size,
                              hipStream_t stream) {
    (void)in_sizes; (void)n_in; (void)out_size; (void)ws_size;
    const float* s     = (const float*)d_in[0];
    const float* z     = (const float*)d_in[1];
    const float* rot   = (const float*)d_in[2];
    const float* trans = (const float*)d_in[3];
    const float* mask  = (const float*)d_in[4];
    const float* wq    = (const float*)d_in[5];
    const float* bq    = (const float*)d_in[6];
    const float* wkv   = (const float*)d_in[7];
    const float* bkv   = (const float*)d_in[8];
    const float* wqp   = (const float*)d_in[9];
    const float* bqp   = (const float*)d_in[10];
    const float* wkvp  = (const float*)d_in[11];
    const float* bkvp  = (const float*)d_in[12];
    const float* wb    = (const float*)d_in[13];
    const float* bb    = (const float*)d_in[14];
    const float* wdz   = (const float*)d_in[15];
    const float* bdz   = (const float*)d_in[16];
    const float* hwts  = (const float*)d_in[17];
    const float* wout  = (const float*)d_in[18];
    const float* bout  = (const float*)d_in[19];
    float* out = (float*)d_out;

    float* ws = (float*)d_ws;
    float* Q     = ws;                       // 147456
    float* KT    = Q     + 147456;           // 147456
    float* VT    = KT    + 147456;           // 147456
    float* QP    = VT    + 147456;           // 110592
    float* KPT   = QP    + 110592;           // 110592
    float* VPT   = KPT   + 110592;           // 221184
    float* O     = VPT   + 221184;           // 147456
    float* OPT   = O     + 147456;           // 221184
    float* OPAIR = OPT   + 221184;           // 294912
    float* BBT   = OPAIR + 294912;           // 7,077,888 floats (28.3 MB)
    ushort16* PZT = (ushort16*)(BBT + 7077888); // 768*768*32 bf16 (37.7 MB)
    // RAW (1152*768 = 884,736 floats, 3.5 MB) aliases BBT: dead before k2 runs.
    float* RAW = BBT;

    hipLaunchKernelGGL(k1a_gemm, dim3(NTOK / 64, 1152 / 64), dim3(256), 0, stream,
                       s, wq, wkv, wqp, wkvp, RAW);
    hipLaunchKernelGGL(k1b_finish, dim3(NTOK / 16), dim3(256), 0, stream,
                       RAW, rot, trans, bq, bkv, bqp, bkvp,
                       Q, KT, VT, QP, KPT, VPT);
    hipLaunchKernelGGL(k2_zproj, dim3(3, NTOK), dim3(256), 0, stream,
                       z, wb, bb, wdz, bdz, BBT, PZT);
    hipLaunchKernelGGL(k3_attn, dim3(NTOK), dim3(768), 0, stream,
                       KT, VT, KPT, VPT, Q, QP, BBT, PZT, mask, hwts,
                       O, OPT, OPAIR);
    hipLaunchKernelGGL(k4_out, dim3(NTOK / K4T), dim3(256), 0, stream,
                       O, OPT, OPAIR, rot, trans, wout, bout, out);
}